// Round 4
// baseline (3173.709 us; speedup 1.0000x reference)
//
#include <hip/hip_runtime.h>
#include <math.h>

// Problem constants (fixed by reference).
#define HIDDEN 1024
#define MEL    80
#define TSTEPS 1000
#define BATCH  64

// R11: 256 persistent blocks x 256 threads (4 waves), 1 block/CU on all 256
// CUs. Block owns 4 hidden units = 16 gate rows. Wave wv owns h-columns
// [wv*256, wv*256+256); within a wave, sub = lane>>4 picks a 64-col window,
// r16 = lane&15 picks the gate row. Per lane: 64 folded weights, 64 FMAs
// (same as the 64x1024 design) but per-SIMD only ONE wave -> MAC issue time
// 213ns -> ~60ns, barrier spans 4 waves not 16, publish is 4 lanes / one
// 16B line. R7 decoupling preserved: wave wv polls exactly the 256 slots
// its own MAC consumes -> no block barrier between poll and MAC.
// Model (R1-R3 counters): polls are XCD-L2 hits (~90ns loop); producer's
// device-scope store snoop-invalidates sharers; per-step fabric cost is
// snoop+refill (~400-600ns) and is NOT reducible by polling tricks (R10:
// same-address in-flight loads MSHR-merge -> staggered poll was a no-op).
// So this round attacks the local-compute half of the step.
// R8 (kept): mailbox packed 4B {tag:8 | h:Q0.23}; quant err 2^-24 << 8.3e-4.
// R9 (kept): AGENT scope. R10 (reverted): staggered poll.
#define NBLK 256
#define TPB  256
#define UPB  4     // units per block

typedef unsigned long long ull;

// v_exp_f32-based activations (abs err ~1e-6 << 8.3e-4 threshold).
__device__ __forceinline__ float sigm_f(float x) { return 1.0f / (1.0f + __expf(-x)); }
__device__ __forceinline__ float tanh_f(float x) { return 1.0f - 2.0f / (1.0f + __expf(2.0f * x)); }

// {tag:8 | q:24}, q = rint(h * 2^23) clamped to +/-(2^23-1).
__device__ __forceinline__ unsigned int pack_h(float h, int tag) {
    int q = (int)rintf(h * 8388608.0f);          // 2^23
    q = max(-8388607, min(8388607, q));
    return ((unsigned int)(tag & 0xFF) << 24) | ((unsigned int)q & 0xFFFFFFu);
}
__device__ __forceinline__ float unpack_u(unsigned int v) {
    int q = ((int)(v << 8)) >> 8;                // sext24
    return (float)q * 1.1920928955078125e-7f;    // * 2^-23
}

// LDS h layout: +4-float pad per 64-float chunk so the 4 unique ds_read_b128
// addresses in a wave (sub=0..3, 256B apart unpadded -> same banks) land on
// disjoint bank groups (+4 floats rotates base bank by 4 per sub).
__device__ __forceinline__ int hoff(int col) { return col + ((col >> 6) << 2); }

__global__ __launch_bounds__(TPB) void tts_recur(
    const float* __restrict__ dec_Wih,   // [4096, 80]
    const float* __restrict__ dec_Whh,   // [4096, 1024]
    const float* __restrict__ dec_bih,   // [4096]
    const float* __restrict__ dec_bhh,   // [4096]
    const float* __restrict__ lin_W,     // [80, 1024]
    const float* __restrict__ lin_b,     // [80]
    float* __restrict__ h_hist,          // [TSTEPS, 1024] (for epilogue)
    unsigned int* __restrict__ hbuf)     // [2, 1024] packed {tag:8|q:24}
{
    const int tid  = threadIdx.x;        // 0..255
    const int blk  = blockIdx.x;         // 0..255
    const int wv   = tid >> 6;           // 0..3
    const int lane = tid & 63;
    const int sub  = lane >> 4;          // 0..3: 64-col window within wave
    const int r16  = lane & 15;          // gate row: gate = r16>>2, j = r16&3
    const int unit0 = blk * UPB;
    const int row_g = (r16 >> 2) * HIDDEN + unit0 + (r16 & 3);
    const int colbase = wv * 256 + sub * 64;

    // Producer wave gets issue priority over the 3 spinning consumer waves.
    if (wv == 0) __builtin_amdgcn_s_setprio(3);

    __shared__ __align__(16) float hEx[HIDDEN + 64];  // 16 chunks x 4-float pad
    __shared__ float part[2][16 * 17];                // [row][wv*4+sub], pitch 17

    // ---- one-time fold: w = Whh_row_window + Wih_row @ lin_W_window ----
    const float* wih = dec_Wih + (size_t)row_g * MEL;
    const float* whh = dec_Whh + (size_t)row_g * HIDDEN + colbase;
    float4 w[16];
#pragma unroll
    for (int k = 0; k < 16; ++k)
        w[k] = *(const float4*)(whh + k * 4);
#pragma unroll 1
    for (int m = 0; m < MEL; ++m) {
        const float aw = wih[m];
        const float4* lw4 = (const float4*)(lin_W + (size_t)m * HIDDEN + colbase);
#pragma unroll
        for (int k = 0; k < 8; ++k) {
            const float4 lw = lw4[k];
            w[k].x = fmaf(aw, lw.x, w[k].x); w[k].y = fmaf(aw, lw.y, w[k].y);
            w[k].z = fmaf(aw, lw.z, w[k].z); w[k].w = fmaf(aw, lw.w, w[k].w);
        }
#pragma unroll
        for (int k = 8; k < 16; ++k) {
            const float4 lw = lw4[k];
            w[k].x = fmaf(aw, lw.x, w[k].x); w[k].y = fmaf(aw, lw.y, w[k].y);
            w[k].z = fmaf(aw, lw.z, w[k].z); w[k].w = fmaf(aw, lw.w, w[k].w);
        }
    }
    float b_comb_r = dec_bih[row_g] + dec_bhh[row_g];
    const float b_dec_r = b_comb_r;                  // step 0 (x=0, no lin_b fold)
    for (int m = 0; m < MEL; ++m)
        b_comb_r = fmaf(wih[m], lin_b[m], b_comb_r);

    float c_prev = 0.0f;                             // live on wave0 lanes 0..3

    // ---- step 0: g = b_dec (h=c=x=0); wave 0 only ----
    if (wv == 0) {
        const float g = b_dec_r;                     // lane L<16 holds row L
        const int j = lane & 3;
        const float gi = __shfl(g, j, 64);
        const float gg = __shfl(g, 8 + j, 64);
        const float go = __shfl(g, 12 + j, 64);
        const float c  = sigm_f(gi) * tanh_f(gg);    // f-gate * c0 = 0
        const float h  = sigm_f(go) * tanh_f(c);
        c_prev = c;
        if (lane < 4) {
            __hip_atomic_store(hbuf + unit0 + lane, pack_h(h, 1),
                               __ATOMIC_RELAXED, __HIP_MEMORY_SCOPE_AGENT);
            h_hist[unit0 + lane] = h;
        }
    }

    // ---- steps 1..TSTEPS-1 ----
    for (int t = 1; t < TSTEPS; ++t) {
        const int buf = t & 1;
        // Poll 4 own slots (one 16B line region) as 2x8B atomic loads.
        // Tag travels with value in each 4B word -> no fences. 0xAA poison
        // (tag 170) never matches the first polls (want 1 or 2).
        {
            const ull* src = (const ull*)(hbuf + ((t - 1) & 1) * HIDDEN) + tid * 2;
            const unsigned int want = (unsigned int)t & 0xFFu;
            ull a = __hip_atomic_load(src,     __ATOMIC_RELAXED, __HIP_MEMORY_SCOPE_AGENT);
            ull b = __hip_atomic_load(src + 1, __ATOMIC_RELAXED, __HIP_MEMORY_SCOPE_AGENT);
            while ((((unsigned)(a >> 24)) & 0xFFu) != want ||
                   ((unsigned)(a >> 56))          != want ||
                   (((unsigned)(b >> 24)) & 0xFFu) != want ||
                   ((unsigned)(b >> 56))          != want) {
                a = __hip_atomic_load(src,     __ATOMIC_RELAXED, __HIP_MEMORY_SCOPE_AGENT);
                b = __hip_atomic_load(src + 1, __ATOMIC_RELAXED, __HIP_MEMORY_SCOPE_AGENT);
            }
            float4 hv;
            hv.x = unpack_u((unsigned)a);
            hv.y = unpack_u((unsigned)(a >> 32));
            hv.z = unpack_u((unsigned)b);
            hv.w = unpack_u((unsigned)(b >> 32));
            *(float4*)&hEx[hoff(tid * 4)] = hv;      // wave-private slice
        }
        // Wave-local exchange: per-wave DS ops execute in program order (HW);
        // wave_barrier stops compiler reordering (rocPRIM warp-exchange idiom).
        __builtin_amdgcn_wave_barrier();

        // MAC: 16 ds_read_b128 (4 unique addrs/wave, bank-spread by pad) +
        // 64 fma into 4 accumulators. No block barrier needed (R7).
        const float4* hp = (const float4*)&hEx[hoff(colbase)];
        float a0 = 0.f, a1 = 0.f, a2 = 0.f, a3 = 0.f;
#pragma unroll
        for (int k = 0; k < 16; k += 4) {
            const float4 h0 = hp[k], h1 = hp[k + 1], h2 = hp[k + 2], h3 = hp[k + 3];
            a0 = fmaf(w[k].x, h0.x, a0);   a0 = fmaf(w[k].y, h0.y, a0);
            a0 = fmaf(w[k].z, h0.z, a0);   a0 = fmaf(w[k].w, h0.w, a0);
            a1 = fmaf(w[k+1].x, h1.x, a1); a1 = fmaf(w[k+1].y, h1.y, a1);
            a1 = fmaf(w[k+1].z, h1.z, a1); a1 = fmaf(w[k+1].w, h1.w, a1);
            a2 = fmaf(w[k+2].x, h2.x, a2); a2 = fmaf(w[k+2].y, h2.y, a2);
            a2 = fmaf(w[k+2].z, h2.z, a2); a2 = fmaf(w[k+2].w, h2.w, a2);
            a3 = fmaf(w[k+3].x, h3.x, a3); a3 = fmaf(w[k+3].y, h3.y, a3);
            a3 = fmaf(w[k+3].z, h3.z, a3); a3 = fmaf(w[k+3].w, h3.w, a3);
        }
        part[buf][r16 * 17 + (wv * 4 + sub)] = (a0 + a1) + (a2 + a3);
        __syncthreads();                             // barrier B (only one/step)

        if (wv == 0) {
            // Reduce 16 partials for row = lane (<16), then in-wave gates.
            float g = 0.0f;
            if (lane < 16) {
                const float* pr = &part[buf][lane * 17];
                float p[16];
#pragma unroll
                for (int i = 0; i < 16; ++i) p[i] = pr[i];
                const float s = (((p[0]+p[1])+(p[2]+p[3])) + ((p[4]+p[5])+(p[6]+p[7])))
                              + (((p[8]+p[9])+(p[10]+p[11])) + ((p[12]+p[13])+(p[14]+p[15])));
                g = s + b_comb_r;
            }
            const int j = lane & 3;
            const float gi = __shfl(g, j, 64);
            const float gf = __shfl(g, 4 + j, 64);
            const float gg = __shfl(g, 8 + j, 64);
            const float go = __shfl(g, 12 + j, 64);
            const float c  = sigm_f(gf) * c_prev + sigm_f(gi) * tanh_f(gg);
            const float h  = sigm_f(go) * tanh_f(c);
            c_prev = c;
            if (lane < 4) {
                __hip_atomic_store(hbuf + buf * HIDDEN + unit0 + lane, pack_h(h, t + 1),
                                   __ATOMIC_RELAXED, __HIP_MEMORY_SCOPE_AGENT);
                h_hist[(size_t)t * HIDDEN + unit0 + lane] = h;
            }
        }
        // Race-freedom (NBLK-independent, same proof as 64-block version):
        // part is double-buffered across the single barrier B. hEx slices are
        // wave-private with program-order write-after-read. hbuf overwrite:
        // h(t+1) overwrites h(t-1) in buf^1 only after its producer observed
        // ALL tags t+1 <- every block published h(t) <- every block consumed
        // h(t-1). Values+tags travel atomically per 4B word, so a later
        // overwrite cannot corrupt already-loaded registers. 8-bit tag: slot
        // lag <=2 steps << 256.
    }
}

// Epilogue: frame[t] = lin_W @ h[t] + lin_b, broadcast to 64 batch rows.
__global__ __launch_bounds__(128) void tts_frames(
    const float* __restrict__ lin_W, const float* __restrict__ lin_b,
    const float* __restrict__ h_hist, float* __restrict__ out)
{
    const int t = blockIdx.x;
    const int tid = threadIdx.x;
    __shared__ __align__(16) float h_sh[HIDDEN];
    __shared__ float f_s[MEL];
    const float4* src = (const float4*)(h_hist + (size_t)t * HIDDEN);
    ((float4*)h_sh)[tid] = src[tid];
    ((float4*)h_sh)[tid + 128] = src[tid + 128];
    __syncthreads();
    if (tid < MEL) {
        const float* wrow = lin_W + (size_t)tid * HIDDEN;
        float acc = lin_b[tid];
#pragma unroll 8
        for (int c = 0; c < HIDDEN; ++c)
            acc = fmaf(wrow[c], h_sh[c], acc);
        f_s[tid] = acc;
    }
    __syncthreads();
    for (int idx = tid; idx < BATCH * MEL; idx += 128) {
        const int b = idx / MEL;
        const int m = idx - b * MEL;
        out[(size_t)b * TSTEPS * MEL + (size_t)t * MEL + m] = f_s[m];
    }
}

extern "C" void kernel_launch(void* const* d_in, const int* in_sizes, int n_in,
                              void* d_out, int out_size, void* d_ws, size_t ws_size,
                              hipStream_t stream) {
    // Inputs: 0 text, 1 text_lens, 2 max_audio_len, 3 W_emb, 4..7 enc_*,
    // 8..11 dec_{Wih,Whh,bih,bhh}, 12 lin_W, 13 lin_b. Encoder is dead code.
    const float* dec_Wih = (const float*)d_in[8];
    const float* dec_Whh = (const float*)d_in[9];
    const float* dec_bih = (const float*)d_in[10];
    const float* dec_bhh = (const float*)d_in[11];
    const float* lin_W   = (const float*)d_in[12];
    const float* lin_b   = (const float*)d_in[13];
    float* out = (float*)d_out;

    // Workspace: h_hist fp32 [1000][1024] (4,096,000 B) + hbuf [2][1024] uint.
    // 0xAA poison -> tag byte 170 never matches the first polls -> no init pass.
    float* h_hist = (float*)d_ws;
    unsigned int* hbuf = (unsigned int*)((char*)d_ws + (size_t)TSTEPS * HIDDEN * sizeof(float));

    hipLaunchKernelGGL(tts_recur, dim3(NBLK), dim3(TPB), 0, stream,
                       dec_Wih, dec_Whh, dec_bih, dec_bhh, lin_W, lin_b, h_hist, hbuf);
    hipLaunchKernelGGL(tts_frames, dim3(TSTEPS), dim3(128), 0, stream,
                       lin_W, lin_b, h_hist, out);
}

// Round 5
// 2203.610 us; speedup vs baseline: 1.4402x; 1.4402x over previous
//
#include <hip/hip_runtime.h>
#include <math.h>

// Problem constants (fixed by reference).
#define HIDDEN 1024
#define MEL    80
#define TSTEPS 1000
#define BATCH  64

// 64 persistent blocks x 1024 threads (16 waves). Block owns 16 hidden units
// = 64 gate rows (one full 64B mailbox line per producer -- R4 showed
// multi-writer lines are poison: false sharing + 2x write amplification).
// Wave wv owns column slice [wv*64, wv*64+64); lane = gate row in MAC phase,
// lane = column (slot 64*wv+lane) in the poll phase. A wave's MAC needs ONLY
// the 64 h values its own lanes poll -> no block barrier between poll and
// MAC; the single per-step __syncthreads (B) sits before wave0's reduction.
// R8 (kept): 4B packed {tag:8 | h:Q0.23}; quant err 2^-24 << 8.3e-4.
// R9 (kept): AGENT scope (== SYSTEM on this HW per counters).
// R10/R11 (reverted): staggered poll (MSHR-merge null), 256-block spread
// (false-sharing regression).
// R12: arrival-order chunked MAC. Fabric term (publish->invalidate->refill,
// ~1.2-1.4us/step) is structural; the reducible tail is the 64-FMA MAC that
// previously ran strictly AFTER the last of 4 producer lines arrived. Each
// wave's 64 cols = 4 chunks of 16, chunk c == producer block 4*wv+c's line.
// Per poll iteration, __ballot finds fully-arrived chunks; their 16 FMAs run
// immediately, hiding under the wait for stragglers. Only the last chunk's
// ~128cy remains serial. Deterministic: fixed per-chunk accumulators combined
// in fixed order.
#define NBLK 64
#define TPB  1024

typedef unsigned long long ull;

// v_exp_f32-based activations (abs err ~1e-6 << 8.3e-4 threshold).
__device__ __forceinline__ float sigm_f(float x) { return 1.0f / (1.0f + __expf(-x)); }
__device__ __forceinline__ float tanh_f(float x) { return 1.0f - 2.0f / (1.0f + __expf(2.0f * x)); }

// {tag:8 | q:24}, q = rint(h * 2^23) clamped to +/-(2^23-1).
__device__ __forceinline__ unsigned int pack_h(float h, int tag) {
    int q = (int)rintf(h * 8388608.0f);          // 2^23
    q = max(-8388607, min(8388607, q));
    return ((unsigned int)(tag & 0xFF) << 24) | ((unsigned int)q & 0xFFFFFFu);
}
__device__ __forceinline__ float unpack_u(unsigned int v) {
    int q = ((int)(v << 8)) >> 8;                // sext24
    return (float)q * 1.1920928955078125e-7f;    // * 2^-23
}

__global__ __launch_bounds__(TPB, 4) void tts_recur(
    const float* __restrict__ dec_Wih,   // [4096, 80]
    const float* __restrict__ dec_Whh,   // [4096, 1024]
    const float* __restrict__ dec_bih,   // [4096]
    const float* __restrict__ dec_bhh,   // [4096]
    const float* __restrict__ lin_W,     // [80, 1024]
    const float* __restrict__ lin_b,     // [80]
    float* __restrict__ h_hist,          // [TSTEPS, 1024] (for epilogue)
    unsigned int* __restrict__ hbuf)     // [2, 1024] packed {tag:8|q:24}
{
    const int tid  = threadIdx.x;
    const int blk  = blockIdx.x;
    const int wv   = tid >> 6;           // 0..15: column slice / slot chunk
    const int lane = tid & 63;           // gate row (MAC) / column (poll)
    const int jj   = lane & 15;          // unit within block
    const int gate = lane >> 4;          // i,f,g,o
    const int unit_g = blk * 16 + jj;
    const int row_g  = gate * HIDDEN + unit_g;

    // Producer wave gets issue priority over the 15 spinning consumer waves.
    if (wv == 0) __builtin_amdgcn_s_setprio(3);

    __shared__ __align__(16) float hEx[16][64];   // per-wave h slice (single buffer:
                                                  // wave-private; chunk reads happen
                                                  // only after ballot-gated writes,
                                                  // steps separated by barrier B)
    __shared__ float part[2][64 * 17];            // partials, pitch 17 (2-way = free)

    // ---- one-time fold: w = Whh_row_slice + Wih_row @ lin_W_slice (regs) ----
    const float* wih = dec_Wih + (size_t)row_g * MEL;
    const float* whh = dec_Whh + (size_t)row_g * HIDDEN + wv * 64;
    float4 w[16];
#pragma unroll
    for (int k = 0; k < 16; ++k)
        w[k] = *(const float4*)(whh + k * 4);
#pragma unroll 1
    for (int m = 0; m < MEL; ++m) {
        const float aw = wih[m];
        const float4* lw4 = (const float4*)(lin_W + (size_t)m * HIDDEN + wv * 64);
#pragma unroll
        for (int k = 0; k < 8; ++k) {
            const float4 lw = lw4[k];
            w[k].x = fmaf(aw, lw.x, w[k].x); w[k].y = fmaf(aw, lw.y, w[k].y);
            w[k].z = fmaf(aw, lw.z, w[k].z); w[k].w = fmaf(aw, lw.w, w[k].w);
        }
#pragma unroll
        for (int k = 8; k < 16; ++k) {
            const float4 lw = lw4[k];
            w[k].x = fmaf(aw, lw.x, w[k].x); w[k].y = fmaf(aw, lw.y, w[k].y);
            w[k].z = fmaf(aw, lw.z, w[k].z); w[k].w = fmaf(aw, lw.w, w[k].w);
        }
    }
    float b_comb_r = dec_bih[row_g] + dec_bhh[row_g];
    const float b_dec_r = b_comb_r;                  // step 0 (x=0, no lin_b fold)
    for (int m = 0; m < MEL; ++m)
        b_comb_r = fmaf(wih[m], lin_b[m], b_comb_r);

    float c_prev = 0.0f;                             // live on wave 0 lanes

    // ---- step 0: g = b_dec (h=c=x=0); wave 0 only ----
    if (wv == 0) {
        const float g = b_dec_r;
        const float gi = __shfl(g, jj, 64);
        const float gg = __shfl(g, 32 + jj, 64);
        const float go = __shfl(g, 48 + jj, 64);
        const float c  = sigm_f(gi) * tanh_f(gg);    // f-gate * c0 = 0
        const float h  = sigm_f(go) * tanh_f(c);
        c_prev = c;
        if (lane < 16) {
            __hip_atomic_store(hbuf + unit_g, pack_h(h, 1),
                               __ATOMIC_RELAXED, __HIP_MEMORY_SCOPE_AGENT);
            h_hist[unit_g] = h;
        }
    }

    // ---- steps 1..TSTEPS-1 ----
    for (int t = 1; t < TSTEPS; ++t) {
        const int buf = t & 1;
        // Arrival-order chunked poll+MAC. Lane polls its own slot (tag==t&0xFF,
        // tag travels with the value in one 4B word -> no fences; 0xAA poison
        // never matches). When all 16 lanes of chunk c (= producer block
        // 4*wv+c's line) have arrived, MAC that chunk immediately.
        {
            const unsigned int* src = hbuf + ((t - 1) & 1) * HIDDEN + tid;
            const unsigned int want = (unsigned int)t & 0xFFu;
            bool mine = false;
            unsigned int pending = 0xFu;
            float cs0 = 0.f, cs1 = 0.f, cs2 = 0.f, cs3 = 0.f;
            const float4* hp = (const float4*)&hEx[wv][0];
            do {
                if (!mine) {
                    const unsigned int v = __hip_atomic_load(src, __ATOMIC_RELAXED,
                                                             __HIP_MEMORY_SCOPE_AGENT);
                    if ((v >> 24) == want) { hEx[wv][lane] = unpack_u(v); mine = true; }
                }
                // Fence: chunk ds_reads below must not be hoisted above the
                // ds_writes (per-wave DS ops execute in program order in HW;
                // wave_barrier stops compiler reordering).
                __builtin_amdgcn_wave_barrier();
                const ull rdy = __ballot(mine);
#pragma unroll
                for (int c = 0; c < 4; ++c) {
                    if ((pending >> c) & 1u) {
                        if (((rdy >> (16 * c)) & 0xFFFFull) == 0xFFFFull) {
                            const float4 h0 = hp[4*c], h1 = hp[4*c+1],
                                         h2 = hp[4*c+2], h3 = hp[4*c+3];
                            const float4 w0 = w[4*c], w1 = w[4*c+1],
                                         w2 = w[4*c+2], w3 = w[4*c+3];
                            float s0 = 0.f, s1 = 0.f;
                            s0 = fmaf(w0.x, h0.x, s0); s1 = fmaf(w0.y, h0.y, s1);
                            s0 = fmaf(w0.z, h0.z, s0); s1 = fmaf(w0.w, h0.w, s1);
                            s0 = fmaf(w1.x, h1.x, s0); s1 = fmaf(w1.y, h1.y, s1);
                            s0 = fmaf(w1.z, h1.z, s0); s1 = fmaf(w1.w, h1.w, s1);
                            s0 = fmaf(w2.x, h2.x, s0); s1 = fmaf(w2.y, h2.y, s1);
                            s0 = fmaf(w2.z, h2.z, s0); s1 = fmaf(w2.w, h2.w, s1);
                            s0 = fmaf(w3.x, h3.x, s0); s1 = fmaf(w3.y, h3.y, s1);
                            s0 = fmaf(w3.z, h3.z, s0); s1 = fmaf(w3.w, h3.w, s1);
                            const float cs = s0 + s1;
                            if (c == 0) cs0 = cs; else if (c == 1) cs1 = cs;
                            else if (c == 2) cs2 = cs; else cs3 = cs;
                            pending &= ~(1u << c);
                        }
                    }
                }
                // Disjointness: pending writers' slots belong to chunks that
                // have NOT fired; fired-chunk reads touch only arrived slots
                // whose lanes write no more this step. Deterministic combine:
            } while (pending);
            part[buf][lane * 17 + wv] = (cs0 + cs1) + (cs2 + cs3);
        }
        __syncthreads();                               // barrier B (only one/step)

        if (wv == 0) {
            // Reduce 16 partials for this lane's row, then in-wave gates.
            const float* pr = &part[buf][lane * 17];
            float p[16];
#pragma unroll
            for (int i = 0; i < 16; ++i) p[i] = pr[i];
            const float s = (((p[0]+p[1])+(p[2]+p[3])) + ((p[4]+p[5])+(p[6]+p[7])))
                          + (((p[8]+p[9])+(p[10]+p[11])) + ((p[12]+p[13])+(p[14]+p[15])));
            const float g = s + b_comb_r;
            const float gi = __shfl(g, jj, 64);
            const float gf = __shfl(g, 16 + jj, 64);
            const float gg = __shfl(g, 32 + jj, 64);
            const float go = __shfl(g, 48 + jj, 64);
            const float c  = sigm_f(gf) * c_prev + sigm_f(gi) * tanh_f(gg);
            const float h  = sigm_f(go) * tanh_f(c);
            c_prev = c;
            if (lane < 16) {
                __hip_atomic_store(hbuf + buf * HIDDEN + unit_g, pack_h(h, t + 1),
                                   __ATOMIC_RELAXED, __HIP_MEMORY_SCOPE_AGENT);
                h_hist[(size_t)t * HIDDEN + unit_g] = h;
            }
        }
        // Race-freedom: part is double-buffered across barrier B. hEx is
        // wave-private; within a step, chunk reads are ballot-gated after all
        // 16 writes; across steps, barrier B separates. hbuf overwrite:
        // h(t+1) overwrites h(t-1) only after its producer observed ALL tags
        // t+1 <- every block published h(t) <- every block consumed h(t-1).
        // 8-bit tag: slot lag <=2 steps << 256 -> no aliasing.
    }
}

// Epilogue: frame[t] = lin_W @ h[t] + lin_b, broadcast to 64 batch rows.
__global__ __launch_bounds__(128) void tts_frames(
    const float* __restrict__ lin_W, const float* __restrict__ lin_b,
    const float* __restrict__ h_hist, float* __restrict__ out)
{
    const int t = blockIdx.x;
    const int tid = threadIdx.x;
    __shared__ __align__(16) float h_sh[HIDDEN];
    __shared__ float f_s[MEL];
    const float4* src = (const float4*)(h_hist + (size_t)t * HIDDEN);
    ((float4*)h_sh)[tid] = src[tid];
    ((float4*)h_sh)[tid + 128] = src[tid + 128];
    __syncthreads();
    if (tid < MEL) {
        const float* wrow = lin_W + (size_t)tid * HIDDEN;
        float acc = lin_b[tid];
#pragma unroll 8
        for (int c = 0; c < HIDDEN; ++c)
            acc = fmaf(wrow[c], h_sh[c], acc);
        f_s[tid] = acc;
    }
    __syncthreads();
    for (int idx = tid; idx < BATCH * MEL; idx += 128) {
        const int b = idx / MEL;
        const int m = idx - b * MEL;
        out[(size_t)b * TSTEPS * MEL + (size_t)t * MEL + m] = f_s[m];
    }
}

extern "C" void kernel_launch(void* const* d_in, const int* in_sizes, int n_in,
                              void* d_out, int out_size, void* d_ws, size_t ws_size,
                              hipStream_t stream) {
    // Inputs: 0 text, 1 text_lens, 2 max_audio_len, 3 W_emb, 4..7 enc_*,
    // 8..11 dec_{Wih,Whh,bih,bhh}, 12 lin_W, 13 lin_b. Encoder is dead code.
    const float* dec_Wih = (const float*)d_in[8];
    const float* dec_Whh = (const float*)d_in[9];
    const float* dec_bih = (const float*)d_in[10];
    const float* dec_bhh = (const float*)d_in[11];
    const float* lin_W   = (const float*)d_in[12];
    const float* lin_b   = (const float*)d_in[13];
    float* out = (float*)d_out;

    // Workspace: h_hist fp32 [1000][1024] (4,096,000 B) + hbuf [2][1024] uint.
    // 0xAA poison -> tag byte 170 never matches the first polls -> no init pass.
    float* h_hist = (float*)d_ws;
    unsigned int* hbuf = (unsigned int*)((char*)d_ws + (size_t)TSTEPS * HIDDEN * sizeof(float));

    hipLaunchKernelGGL(tts_recur, dim3(NBLK), dim3(TPB), 0, stream,
                       dec_Wih, dec_Whh, dec_bih, dec_bhh, lin_W, lin_b, h_hist, hbuf);
    hipLaunchKernelGGL(tts_frames, dim3(TSTEPS), dim3(128), 0, stream,
                       lin_W, lin_b, h_hist, out);
}